// Round 8
// baseline (166.761 us; speedup 1.0000x reference)
//
#include <hip/hip_runtime.h>
#include <math.h>

#define BB 128   // batch
#define TT 8     // seq
#define DD 2048  // model dim
#define RR 4     // TT rank
#define VV 512   // vocab

typedef __attribute__((ext_vector_type(8))) short short8;
typedef __attribute__((ext_vector_type(4))) float v4f;

__device__ __forceinline__ unsigned pack_bf16(float x, float y) {
    union { float f; unsigned u; } a, b;
    a.f = x; b.f = y;
    unsigned ua = a.u + 0x7fffu + ((a.u >> 16) & 1u);
    unsigned ub = b.u + 0x7fffu + ((b.u >> 16) & 1u);
    return (ua >> 16) | (ub & 0xffff0000u);
}

// ---------------- phase A: T-mean -> fmb(bf16), alpha/beta partial dots ----------------
// grid 256 = (b, half-of-D). Partials deterministic per (b,half); zeroes marg.
__global__ __launch_bounds__(256) void phaseA(const float* __restrict__ inp,
                                              const float* __restrict__ w_alpha,
                                              const float* __restrict__ w_beta,
                                              unsigned short* __restrict__ fmb,
                                              float* __restrict__ alphaP,
                                              float* __restrict__ betaP,
                                              float* __restrict__ marg) {
    int bid = blockIdx.x;
    int b = bid >> 1, half = bid & 1;
    int tid = threadIdx.x;

    if (bid < 8) marg[bid * 256 + tid] = 0.f;   // zero marg (2048 floats)

    const float* base = inp + (size_t)b * TT * DD;
    float pa[4] = {0.f, 0.f, 0.f, 0.f};
    float pb[4] = {0.f, 0.f, 0.f, 0.f};
#pragma unroll
    for (int i = 0; i < 4; ++i) {
        int d = half * 1024 + i * 256 + tid;
        float s = 0.f;
#pragma unroll
        for (int t = 0; t < TT; ++t) s += base[t * DD + d];
        float v = s * (1.0f / TT);
        union { float f; unsigned u; } cv; cv.f = v;
        unsigned r = cv.u + 0x7fffu + ((cv.u >> 16) & 1u);
        fmb[b * DD + d] = (unsigned short)(r >> 16);
        float4 wa = *(const float4*)(w_alpha + d * 4);
        float4 wb = *(const float4*)(w_beta + d * 4);
        pa[0] += v * wa.x; pa[1] += v * wa.y; pa[2] += v * wa.z; pa[3] += v * wa.w;
        pb[0] += v * wb.x; pb[1] += v * wb.y; pb[2] += v * wb.z; pb[3] += v * wb.w;
    }
#pragma unroll
    for (int r = 0; r < 4; ++r) {
        for (int m = 1; m < 64; m <<= 1) {
            pa[r] += __shfl_xor(pa[r], m);
            pb[r] += __shfl_xor(pb[r], m);
        }
    }
    __shared__ float sA[4][4], sB[4][4];
    int wid = tid >> 6;
    if ((tid & 63) == 0) {
#pragma unroll
        for (int r = 0; r < 4; ++r) { sA[wid][r] = pa[r]; sB[wid][r] = pb[r]; }
    }
    __syncthreads();
    if (tid < 4) {
        alphaP[b * 8 + half * 4 + tid] = sA[0][tid] + sA[1][tid] + sA[2][tid] + sA[3][tid];
        betaP [b * 8 + half * 4 + tid] = sB[0][tid] + sB[1][tid] + sB[2][tid] + sB[3][tid];
    }
}

// ---------------- phase B: no-LDS no-barrier direct-MFMA GEMM -> C^T partials ----------
// v8: computes D = C^T tile: D[i=n][j=m] = sum_k wv[k][n] * fmb[m][k].
// A-frag (row=lane&15, k=(lane>>4)*8+j)  <- wv columns, 8 scalar f32 loads + pack (verified layout)
// B-frag (col=lane&15, k-contiguous s8)  <- fmb rows DIRECT (verified layout, L2-resident)
// D      (row=q*4+r,  col=m15)           -> Cpart[qrt][n][m] (verified layout)
// wave = (n-tile of 16, K-quarter of 512): 2048 waves = 256 blocks x 8 waves.
// Zero LDS, zero barriers: waves fully independent; HBM pace is the only coupling.
__global__ __launch_bounds__(512, 4) void phaseB(const unsigned short* __restrict__ fmb,
                                                 const float* __restrict__ wv,
                                                 float* __restrict__ Cpart) {
    const int tid = threadIdx.x;
    const int bid = blockIdx.x;        // 0..255
    const int w = tid >> 6;            // 0..7
    const int lane = tid & 63;
    const int m15 = lane & 15;
    const int q = lane >> 4;           // 0..3

    const int nt  = bid * 2 + (w >> 2);   // n-tile 0..511 (block = 2 tiles = one 128B line col)
    const int qrt = w & 3;                // K-quarter
    const int n0  = nt * 16;
    const int k0  = qrt * 512;

    const float* wp = wv + (size_t)(k0 + q * 8) * 8192 + n0 + m15;          // + (c*32+j)*8192
    const unsigned short* fb = fmb + (size_t)m15 * DD + k0 + q * 8;         // + mt*16*DD + c*32

    v4f acc[8];
#pragma unroll
    for (int mt = 0; mt < 8; ++mt) acc[mt] = (v4f){0.f, 0.f, 0.f, 0.f};

    float af[8], afn[8];
#pragma unroll
    for (int j = 0; j < 8; ++j) af[j] = wp[(size_t)j * 8192];

    for (int c = 0; c < 16; ++c) {
        // issue next chunk's A loads early (HBM latency hides under this chunk's work)
        if (c < 15) {
            const float* wn = wp + (size_t)(c + 1) * 32 * 8192;
#pragma unroll
            for (int j = 0; j < 8; ++j) afn[j] = wn[(size_t)j * 8192];
        }
        // pack current A f32 -> bf16 frag
        short8 afr;
        unsigned* au = (unsigned*)&afr;
#pragma unroll
        for (int p = 0; p < 4; ++p) au[p] = pack_bf16(af[2 * p], af[2 * p + 1]);
        // B frags direct from fmb (L2), then 8 MFMAs
        short8 bfr[8];
#pragma unroll
        for (int mt = 0; mt < 8; ++mt)
            bfr[mt] = *(const short8*)(fb + (size_t)mt * 16 * DD + c * 32);
#pragma unroll
        for (int mt = 0; mt < 8; ++mt)
            acc[mt] = __builtin_amdgcn_mfma_f32_16x16x32_bf16(afr, bfr[mt], acc[mt], 0, 0, 0);
        if (c < 15) {
#pragma unroll
            for (int j = 0; j < 8; ++j) af[j] = afn[j];
        }
    }

    // store C^T partial: Cpart[qrt][n0 + q*4 + r][mt*16 + m15]
    float* cb = Cpart + ((size_t)qrt * 8192 + n0) * 128;
#pragma unroll
    for (int r = 0; r < 4; ++r) {
        const int rowoff = (q * 4 + r) * 128;
#pragma unroll
        for (int mt = 0; mt < 8; ++mt)
            cb[rowoff + mt * 16 + m15] = acc[mt][r];
    }
}

// ---------------- phase C: combine K-quarters, abs, marg atomics + label-select ----------
// grid 256 = n-slab of 32 (one r1 index i = s>>6, 8 v's). Coalesced Cpart reads,
// LDS-transposed Cabs[n_local][m], then marg partial sums + sel scatter.
__global__ __launch_bounds__(256) void phaseC(const float* __restrict__ Cpart,
                                              const int* __restrict__ labels,
                                              float* __restrict__ marg,
                                              float* __restrict__ sel) {
    const int s = blockIdx.x;          // slab: n = s*32 .. s*32+32
    const int tid = threadIdx.x;
    const int i = s >> 6;              // r1 index 0..3
    const int v0 = (s & 63) * 8;       // first v in slab
    __shared__ float Cabs[32][132];    // [n_local][m], padded

    const int nl = tid >> 3;           // 0..31
    const int m0 = (tid & 7) * 16;     // 0..112
    const size_t QS = (size_t)8192 * 128;
    const float* cp = Cpart + ((size_t)s * 32 + nl) * 128 + m0;
#pragma unroll
    for (int g = 0; g < 4; ++g) {
        float4 a0 = *(const float4*)(cp + g * 4);
        float4 a1 = *(const float4*)(cp + QS + g * 4);
        float4 a2 = *(const float4*)(cp + 2 * QS + g * 4);
        float4 a3 = *(const float4*)(cp + 3 * QS + g * 4);
        Cabs[nl][m0 + g * 4 + 0] = fabsf(a0.x + a1.x + a2.x + a3.x);
        Cabs[nl][m0 + g * 4 + 1] = fabsf(a0.y + a1.y + a2.y + a3.y);
        Cabs[nl][m0 + g * 4 + 2] = fabsf(a0.z + a1.z + a2.z + a3.z);
        Cabs[nl][m0 + g * 4 + 3] = fabsf(a0.w + a1.w + a2.w + a3.w);
    }
    __syncthreads();

    // marg: thread t<128 -> m=t; sum the slab's 8 v's per j, one atomic per (m,j)
    if (tid < 128) {
#pragma unroll
        for (int j = 0; j < 4; ++j) {
            float sj = 0.f;
#pragma unroll
            for (int vv = 0; vv < 8; ++vv) sj += Cabs[vv * 4 + j][tid];
            atomicAdd(&marg[tid * 16 + i * 4 + j], sj);
        }
    }

    // sel: 1024 (m,t) pairs, 4 per thread; write the 4 j's for our i if label in slab
#pragma unroll
    for (int p = 0; p < 4; ++p) {
        const int mt_idx = tid * 4 + p;         // m*8 + t
        const int lv = labels[mt_idx];
        if (lv >= v0 && lv < v0 + 8) {
            const int nb = (lv - v0) * 4;
#pragma unroll
            for (int j = 0; j < 4; ++j)
                sel[mt_idx * 16 + i * 4 + j] = Cabs[nb + j][mt_idx >> 3];
        }
    }
}

// ---------------- phase D: chain products, normalizer, loss ----------------
__global__ __launch_bounds__(128) void phaseD(const float* __restrict__ alphaP,
                                              const float* __restrict__ betaP,
                                              const float* __restrict__ marg,
                                              const float* __restrict__ sel,
                                              float* __restrict__ out) {
    int b = threadIdx.x;
    const float* sb = sel + b * TT * 16;
    float res[16], tmp[16], mm[16], zm[16];
#pragma unroll
    for (int e = 0; e < 16; ++e) res[e] = sb[e];
    for (int t = 1; t < TT; ++t) {
        const float* m = sb + t * 16;
#pragma unroll
        for (int i = 0; i < 4; ++i)
#pragma unroll
            for (int jj = 0; jj < 4; ++jj) {
                float s = 0.f;
#pragma unroll
                for (int k = 0; k < 4; ++k) s += res[i * 4 + k] * m[k * 4 + jj];
                tmp[i * 4 + jj] = s;
            }
#pragma unroll
        for (int e = 0; e < 16; ++e) res[e] = tmp[e];
    }
#pragma unroll
    for (int e = 0; e < 16; ++e) { mm[e] = marg[b * 16 + e]; zm[e] = mm[e]; }
    for (int st = 0; st < TT; ++st) {
#pragma unroll
        for (int i = 0; i < 4; ++i)
#pragma unroll
            for (int jj = 0; jj < 4; ++jj) {
                float s = 0.f;
#pragma unroll
                for (int k = 0; k < 4; ++k) s += zm[i * 4 + k] * mm[k * 4 + jj];
                tmp[i * 4 + jj] = s;
            }
#pragma unroll
        for (int e = 0; e < 16; ++e) zm[e] = tmp[e];
    }
    float u = 0.f, z = 0.f;
#pragma unroll
    for (int i = 0; i < 4; ++i) {
        float ai = fabsf(alphaP[b * 8 + i] + alphaP[b * 8 + 4 + i]);
#pragma unroll
        for (int jj = 0; jj < 4; ++jj) {
            float bj = fabsf(betaP[b * 8 + jj] + betaP[b * 8 + 4 + jj]);
            u += ai * res[i * 4 + jj] * bj;
            z += ai * zm[i * 4 + jj] * bj;
        }
    }
    float loss = logf(z) - logf(u);
    __shared__ float red[128];
    red[b] = loss;
    __syncthreads();
    for (int off = 64; off >= 1; off >>= 1) {
        if (b < off) red[b] += red[b + off];
        __syncthreads();
    }
    if (b == 0) out[0] = red[0] * (1.0f / BB);
}

extern "C" void kernel_launch(void* const* d_in, const int* in_sizes, int n_in,
                              void* d_out, int out_size, void* d_ws, size_t ws_size,
                              hipStream_t stream) {
    const float* inp     = (const float*)d_in[0];  // [128,8,2048]
    const int*   labels  = (const int*)d_in[1];    // [128,8]
    const float* w_alpha = (const float*)d_in[2];  // [2048,4]
    const float* w_beta  = (const float*)d_in[3];  // [2048,4]
    const float* wv      = (const float*)d_in[4];  // [2048,8192]
    float* out = (float*)d_out;

    float* ws     = (float*)d_ws;
    float* alphaP = ws;                        // 1024 floats
    float* betaP  = ws + 1024;                 // 1024 floats
    float* marg   = ws + 2048;                 // 2048 floats (zeroed by phaseA)
    float* sel    = ws + 4096;                 // 16384 floats (fully written by phaseC)
    unsigned short* fmb = (unsigned short*)(ws + 20480);  // 128*2048 bf16 = 131072 floats
    float* Cpart  = ws + 151552;               // [4][8192][128] f32 = 16 MB (past fmb)

    phaseA<<<256, 256, 0, stream>>>(inp, w_alpha, w_beta, fmb, alphaP, betaP, marg);
    phaseB<<<256, 512, 0, stream>>>(fmb, wv, Cpart);
    phaseC<<<256, 256, 0, stream>>>(Cpart, labels, marg, sel);
    phaseD<<<1, 128, 0, stream>>>(alphaP, betaP, marg, sel, out);
}

// Round 10
// 124.412 us; speedup vs baseline: 1.3404x; 1.3404x over previous
//
#include <hip/hip_runtime.h>
#include <math.h>

#define BB 128   // batch
#define TT 8     // seq
#define DD 2048  // model dim
#define RR 4     // TT rank
#define VV 512   // vocab

typedef __attribute__((ext_vector_type(8))) short short8;
typedef __attribute__((ext_vector_type(4))) float v4f;

// barrier WITHOUT the compiler's vmcnt(0) drain: ds ordering only (lgkmcnt(0)),
// global prefetch loads stay in flight across the barrier.
#define BARSYNC() asm volatile("s_waitcnt lgkmcnt(0)\n\ts_barrier" ::: "memory")

__device__ __forceinline__ unsigned pack_bf16(float x, float y) {
    union { float f; unsigned u; } a, b;
    a.f = x; b.f = y;
    unsigned ua = a.u + 0x7fffu + ((a.u >> 16) & 1u);
    unsigned ub = b.u + 0x7fffu + ((b.u >> 16) & 1u);
    return (ua >> 16) | (ub & 0xffff0000u);
}

// ---------------- phase A: T-mean -> fmb(bf16), alpha/beta partial dots ----------------
// grid 256 = (b, half-of-D). Partials deterministic per (b,half); zeroes marg.
__global__ __launch_bounds__(256) void phaseA(const float* __restrict__ inp,
                                              const float* __restrict__ w_alpha,
                                              const float* __restrict__ w_beta,
                                              unsigned short* __restrict__ fmb,
                                              float* __restrict__ alphaP,
                                              float* __restrict__ betaP,
                                              float* __restrict__ marg) {
    int bid = blockIdx.x;
    int b = bid >> 1, half = bid & 1;
    int tid = threadIdx.x;

    if (bid < 8) marg[bid * 256 + tid] = 0.f;   // zero marg (2048 floats)

    const float* base = inp + (size_t)b * TT * DD;
    float pa[4] = {0.f, 0.f, 0.f, 0.f};
    float pb[4] = {0.f, 0.f, 0.f, 0.f};
#pragma unroll
    for (int i = 0; i < 4; ++i) {
        int d = half * 1024 + i * 256 + tid;
        float s = 0.f;
#pragma unroll
        for (int t = 0; t < TT; ++t) s += base[t * DD + d];
        float v = s * (1.0f / TT);
        union { float f; unsigned u; } cv; cv.f = v;
        unsigned r = cv.u + 0x7fffu + ((cv.u >> 16) & 1u);
        fmb[b * DD + d] = (unsigned short)(r >> 16);
        float4 wa = *(const float4*)(w_alpha + d * 4);
        float4 wb = *(const float4*)(w_beta + d * 4);
        pa[0] += v * wa.x; pa[1] += v * wa.y; pa[2] += v * wa.z; pa[3] += v * wa.w;
        pb[0] += v * wb.x; pb[1] += v * wb.y; pb[2] += v * wb.z; pb[3] += v * wb.w;
    }
#pragma unroll
    for (int r = 0; r < 4; ++r) {
        for (int m = 1; m < 64; m <<= 1) {
            pa[r] += __shfl_xor(pa[r], m);
            pb[r] += __shfl_xor(pb[r], m);
        }
    }
    __shared__ float sA[4][4], sB[4][4];
    int wid = tid >> 6;
    if ((tid & 63) == 0) {
#pragma unroll
        for (int r = 0; r < 4; ++r) { sA[wid][r] = pa[r]; sB[wid][r] = pb[r]; }
    }
    __syncthreads();
    if (tid < 4) {
        alphaP[b * 8 + half * 4 + tid] = sA[0][tid] + sA[1][tid] + sA[2][tid] + sA[3][tid];
        betaP [b * 8 + half * 4 + tid] = sB[0][tid] + sB[1][tid] + sB[2][tid] + sB[3][tid];
    }
}

// ---------------- phase B: bf16 MFMA GEMM, deep pipeline + fused epilogue ----------------
// v9: 4 LDS buffers (buf = chunk & 3), register ring sw[3] (depth-3 global prefetch:
// chunk c+3 issued at step c), BARSYNC only after odd steps (8 barriers vs 32).
// Hazards: step c reads Ws[c&3], writes Ws[(c+2)&3]; each 2-step region touches 4
// distinct buffers; region N's reads and region N+1's rewrites of the same buffers
// are separated by one BARSYNC (lgkmcnt(0) drains the reads).  Fully unrolled ->
// all sw/afr indices compile-time (no scratch demotion).
__global__ __launch_bounds__(512, 2) void phaseB(const unsigned short* __restrict__ fmb,
                                                 const float* __restrict__ wv,
                                                 const int* __restrict__ labels,
                                                 float* __restrict__ margA,
                                                 float* __restrict__ sel) {
    __shared__ unsigned short Ws[4][32][136];  // [buf][n][k+pad], bf16
    __shared__ int slab[BB * TT];

    const int tid = threadIdx.x;
    const int nb = blockIdx.x;
    const int col0 = nb * 32;

    slab[tid] = labels[tid];
    slab[tid + 512] = labels[tid + 512];

    const int nq = tid & 7;        // float4 group within 32 cols
    const int kp = tid >> 3;       // 0..63 -> k pair 2kp, 2kp+1 within 128-chunk
    const int w = tid >> 6;        // wave
    const int lane = tid & 63;
    const int m15 = lane & 15;
    const int q = lane >> 4;

    const float* wbase = wv + (size_t)(2 * kp) * 8192 + col0 + nq * 4;
    const unsigned short* abase = fmb + (w * 16 + m15) * DD + q * 8;

    v4f acc0 = {0.f, 0.f, 0.f, 0.f};
    v4f acc1 = {0.f, 0.f, 0.f, 0.f};
    short8 afr[2][4];              // A-frag double buffer (compile-time indexed)
    float4 sw[3][2];               // wv register ring, depth 3 (compile-time indexed)

    // prologue: issue chunks 0,1,2 -> sw[0..2]; afr[0] <- chunk0; stage chunks 0,1 to LDS
#pragma unroll
    for (int c = 0; c < 3; ++c) {
        const float* p = wbase + (size_t)c * 128 * 8192;
        sw[c][0] = *(const float4*)(p);
        sw[c][1] = *(const float4*)(p + 8192);
    }
#pragma unroll
    for (int ks = 0; ks < 4; ++ks) afr[0][ks] = *(const short8*)(abase + ks * 32);
#pragma unroll
    for (int c = 0; c < 2; ++c) {
        const float* f0 = (const float*)&sw[c][0];
        const float* f1 = (const float*)&sw[c][1];
#pragma unroll
        for (int j = 0; j < 4; ++j)
            *(unsigned*)&Ws[c][nq * 4 + j][2 * kp] = pack_bf16(f0[j], f1[j]);
    }
    BARSYNC();   // chunk2 load (and afr) stay in flight

#pragma unroll
    for (int c = 0; c < 16; ++c) {
        // issue global loads for chunk c+3 into the reg slot freed 2 steps ago
        if (c + 3 < 16) {
            const float* p = wbase + (size_t)(c + 3) * 128 * 8192;
            sw[c % 3][0] = *(const float4*)(p);
            sw[c % 3][1] = *(const float4*)(p + 8192);
        }
        // A-frag for chunk c+1 (fmb, L2-resident)
        if (c + 1 < 16) {
            const unsigned short* ap = abase + (c + 1) * 128;
#pragma unroll
            for (int ks = 0; ks < 4; ++ks) afr[(c + 1) & 1][ks] = *(const short8*)(ap + ks * 32);
        }
        // MFMA: chunk c from Ws[c&3] with afr[c&1]
#pragma unroll
        for (int ks = 0; ks < 4; ++ks) {
            short8 b0 = *(const short8*)&Ws[c & 3][m15][ks * 32 + q * 8];
            short8 b1 = *(const short8*)&Ws[c & 3][16 + m15][ks * 32 + q * 8];
            acc0 = __builtin_amdgcn_mfma_f32_16x16x32_bf16(afr[c & 1][ks], b0, acc0, 0, 0, 0);
            acc1 = __builtin_amdgcn_mfma_f32_16x16x32_bf16(afr[c & 1][ks], b1, acc1, 0, 0, 0);
        }
        // stage chunk c+2 (loaded at step c-1, ~3 steps of latency cover) -> Ws[(c+2)&3]
        if (c + 2 < 16) {
            const float* f0 = (const float*)&sw[(c + 2) % 3][0];
            const float* f1 = (const float*)&sw[(c + 2) % 3][1];
#pragma unroll
            for (int j = 0; j < 4; ++j)
                *(unsigned*)&Ws[(c + 2) & 3][nq * 4 + j][2 * kp] = pack_bf16(f0[j], f1[j]);
        }
        if (c & 1) BARSYNC();   // barrier every 2 chunks
    }

    // epilogue: |acc| -> marg atomics + label-select scatter. D layout: row=q*4+r, col=m15.
    const int vbase = (nb & 63) * 8;
    const int iblk = nb >> 6;
    const int j = m15 & 3;
    const int v0 = vbase + (m15 >> 2);   // col = m15
    const float* a0p = (const float*)&acc0;
    const float* a1p = (const float*)&acc1;
#pragma unroll
    for (int r = 0; r < 4; ++r) {
        int m = w * 16 + q * 4 + r;
        float a0 = fabsf(a0p[r]);        // col = m15       -> v0
        float a1 = fabsf(a1p[r]);        // col = 16 + m15  -> v0 + 4
        float s = a0 + a1;
        s += __shfl_xor(s, 4);
        s += __shfl_xor(s, 8);
        if ((lane & 12) == 0) atomicAdd(&margA[m * 16 + iblk * 4 + j], s);
#pragma unroll
        for (int t = 0; t < TT; ++t) {
            int lv = slab[m * 8 + t];
            if (lv == v0)     sel[(m * 8 + t) * 16 + iblk * 4 + j] = a0;
            if (lv == v0 + 4) sel[(m * 8 + t) * 16 + iblk * 4 + j] = a1;
        }
    }
}

// ---------------- phase D: chain products, normalizer, loss ----------------
__global__ __launch_bounds__(128) void phaseD(const float* __restrict__ alphaP,
                                              const float* __restrict__ betaP,
                                              const float* __restrict__ marg,
                                              const float* __restrict__ sel,
                                              float* __restrict__ out) {
    int b = threadIdx.x;
    const float* sb = sel + b * TT * 16;
    float res[16], tmp[16], mm[16], zm[16];
#pragma unroll
    for (int e = 0; e < 16; ++e) res[e] = sb[e];
    for (int t = 1; t < TT; ++t) {
        const float* m = sb + t * 16;
#pragma unroll
        for (int i = 0; i < 4; ++i)
#pragma unroll
            for (int jj = 0; jj < 4; ++jj) {
                float s = 0.f;
#pragma unroll
                for (int k = 0; k < 4; ++k) s += res[i * 4 + k] * m[k * 4 + jj];
                tmp[i * 4 + jj] = s;
            }
#pragma unroll
        for (int e = 0; e < 16; ++e) res[e] = tmp[e];
    }
#pragma unroll
    for (int e = 0; e < 16; ++e) { mm[e] = marg[b * 16 + e]; zm[e] = mm[e]; }
    for (int st = 0; st < TT; ++st) {
#pragma unroll
        for (int i = 0; i < 4; ++i)
#pragma unroll
            for (int jj = 0; jj < 4; ++jj) {
                float s = 0.f;
#pragma unroll
                for (int k = 0; k < 4; ++k) s += zm[i * 4 + k] * mm[k * 4 + jj];
                tmp[i * 4 + jj] = s;
            }
#pragma unroll
        for (int e = 0; e < 16; ++e) zm[e] = tmp[e];
    }
    float u = 0.f, z = 0.f;
#pragma unroll
    for (int i = 0; i < 4; ++i) {
        float ai = fabsf(alphaP[b * 8 + i] + alphaP[b * 8 + 4 + i]);
#pragma unroll
        for (int jj = 0; jj < 4; ++jj) {
            float bj = fabsf(betaP[b * 8 + jj] + betaP[b * 8 + 4 + jj]);
            u += ai * res[i * 4 + jj] * bj;
            z += ai * zm[i * 4 + jj] * bj;
        }
    }
    float loss = logf(z) - logf(u);
    __shared__ float red[128];
    red[b] = loss;
    __syncthreads();
    for (int off = 64; off >= 1; off >>= 1) {
        if (b < off) red[b] += red[b + off];
        __syncthreads();
    }
    if (b == 0) out[0] = red[0] * (1.0f / BB);
}

extern "C" void kernel_launch(void* const* d_in, const int* in_sizes, int n_in,
                              void* d_out, int out_size, void* d_ws, size_t ws_size,
                              hipStream_t stream) {
    const float* inp     = (const float*)d_in[0];  // [128,8,2048]
    const int*   labels  = (const int*)d_in[1];    // [128,8]
    const float* w_alpha = (const float*)d_in[2];  // [2048,4]
    const float* w_beta  = (const float*)d_in[3];  // [2048,4]
    const float* wv      = (const float*)d_in[4];  // [2048,8192]
    float* out = (float*)d_out;

    float* ws     = (float*)d_ws;
    float* alphaP = ws;                        // 1024 floats
    float* betaP  = ws + 1024;                 // 1024 floats
    float* marg   = ws + 2048;                 // 2048 floats (zeroed by phaseA)
    float* sel    = ws + 4096;                 // 16384 floats (fully written by phaseB)
    unsigned short* fmb = (unsigned short*)(ws + 20480);  // 128*2048 bf16 = 131072 floats

    phaseA<<<256, 256, 0, stream>>>(inp, w_alpha, w_beta, fmb, alphaP, betaP, marg);
    phaseB<<<256, 512, 0, stream>>>(fmb, wv, labels, marg, sel);
    phaseD<<<1, 128, 0, stream>>>(alphaP, betaP, marg, sel, out);
}

// Round 11
// 122.440 us; speedup vs baseline: 1.3620x; 1.0161x over previous
//
#include <hip/hip_runtime.h>
#include <math.h>

#define BB 128   // batch
#define TT 8     // seq
#define DD 2048  // model dim
#define RR 4     // TT rank
#define VV 512   // vocab

typedef __attribute__((ext_vector_type(8))) short short8;
typedef __attribute__((ext_vector_type(4))) float v4f;

// barrier WITHOUT the compiler's vmcnt(0) drain: ds ordering only (lgkmcnt(0)),
// global prefetch loads stay in flight across the barrier.
#define BARSYNC() asm volatile("s_waitcnt lgkmcnt(0)\n\ts_barrier" ::: "memory")

// asm-pinned global loads: compiler cannot sink or rematerialize an asm def,
// so the issue point (and thus prefetch distance) is hardware-guaranteed.
__device__ __forceinline__ void gl4f(float4& d, const float* p) {
    asm volatile("global_load_dwordx4 %0, %1, off" : "=v"(d) : "v"(p));
}
__device__ __forceinline__ void gl4s(short8& d, const unsigned short* p) {
    asm volatile("global_load_dwordx4 %0, %1, off" : "=v"(d) : "v"(p));
}

__device__ __forceinline__ unsigned pack_bf16(float x, float y) {
    union { float f; unsigned u; } a, b;
    a.f = x; b.f = y;
    unsigned ua = a.u + 0x7fffu + ((a.u >> 16) & 1u);
    unsigned ub = b.u + 0x7fffu + ((b.u >> 16) & 1u);
    return (ua >> 16) | (ub & 0xffff0000u);
}

// ---------------- phase A: T-mean -> fmb(bf16), alpha/beta partial dots ----------------
// grid 256 = (b, half-of-D). Partials deterministic per (b,half); zeroes marg.
__global__ __launch_bounds__(256) void phaseA(const float* __restrict__ inp,
                                              const float* __restrict__ w_alpha,
                                              const float* __restrict__ w_beta,
                                              unsigned short* __restrict__ fmb,
                                              float* __restrict__ alphaP,
                                              float* __restrict__ betaP,
                                              float* __restrict__ marg) {
    int bid = blockIdx.x;
    int b = bid >> 1, half = bid & 1;
    int tid = threadIdx.x;

    if (bid < 8) marg[bid * 256 + tid] = 0.f;   // zero marg (2048 floats)

    const float* base = inp + (size_t)b * TT * DD;
    float pa[4] = {0.f, 0.f, 0.f, 0.f};
    float pb[4] = {0.f, 0.f, 0.f, 0.f};
#pragma unroll
    for (int i = 0; i < 4; ++i) {
        int d = half * 1024 + i * 256 + tid;
        float s = 0.f;
#pragma unroll
        for (int t = 0; t < TT; ++t) s += base[t * DD + d];
        float v = s * (1.0f / TT);
        union { float f; unsigned u; } cv; cv.f = v;
        unsigned r = cv.u + 0x7fffu + ((cv.u >> 16) & 1u);
        fmb[b * DD + d] = (unsigned short)(r >> 16);
        float4 wa = *(const float4*)(w_alpha + d * 4);
        float4 wb = *(const float4*)(w_beta + d * 4);
        pa[0] += v * wa.x; pa[1] += v * wa.y; pa[2] += v * wa.z; pa[3] += v * wa.w;
        pb[0] += v * wb.x; pb[1] += v * wb.y; pb[2] += v * wb.z; pb[3] += v * wb.w;
    }
#pragma unroll
    for (int r = 0; r < 4; ++r) {
        for (int m = 1; m < 64; m <<= 1) {
            pa[r] += __shfl_xor(pa[r], m);
            pb[r] += __shfl_xor(pb[r], m);
        }
    }
    __shared__ float sA[4][4], sB[4][4];
    int wid = tid >> 6;
    if ((tid & 63) == 0) {
#pragma unroll
        for (int r = 0; r < 4; ++r) { sA[wid][r] = pa[r]; sB[wid][r] = pb[r]; }
    }
    __syncthreads();
    if (tid < 4) {
        alphaP[b * 8 + half * 4 + tid] = sA[0][tid] + sA[1][tid] + sA[2][tid] + sA[3][tid];
        betaP [b * 8 + half * 4 + tid] = sB[0][tid] + sB[1][tid] + sB[2][tid] + sB[3][tid];
    }
}

// ---------------- phase B: bf16 MFMA GEMM, asm-pinned counted-vmcnt pipeline -------------
// v11: R6 geometry (32-col blocks, chunk=128, Ws[2] ping-pong, BARSYNC) but all global
// loads are asm-pinned and consumed only after a hand-counted s_waitcnt vmcnt(N):
//   step c: issue wv(c+2)[2] + afr(c+1)[4] -> 12 outstanding -> vmcnt(6) retires the
//   PREVIOUS step's batch -> MFMA chunk c (afr[c&1], Ws[c&1]) -> pack wv(c+1)->Ws[(c+1)&1]
//   -> BARSYNC (loads stay in flight).  Taper: vmcnt(4)@c=14, vmcnt(0)@c=15.
// sched_barrier(0) after each waitcnt stops MFMA/pack hoisting above it (rule #18).
__global__ __launch_bounds__(512, 2) void phaseB(const unsigned short* __restrict__ fmb,
                                                 const float* __restrict__ wv,
                                                 const int* __restrict__ labels,
                                                 float* __restrict__ margA,
                                                 float* __restrict__ sel) {
    __shared__ unsigned short Ws[2][32][136];  // [buf][n][k+pad], bf16
    __shared__ int slab[BB * TT];

    const int tid = threadIdx.x;
    const int nb = blockIdx.x;
    const int col0 = nb * 32;

    slab[tid] = labels[tid];
    slab[tid + 512] = labels[tid + 512];

    const int nq = tid & 7;        // float4 group within 32 cols
    const int kp = tid >> 3;       // 0..63 -> k pair 2kp, 2kp+1 within 128-chunk
    const int w = tid >> 6;        // wave
    const int lane = tid & 63;
    const int m15 = lane & 15;
    const int q = lane >> 4;

    const float* wbase = wv + (size_t)(2 * kp) * 8192 + col0 + nq * 4;
    const unsigned short* abase = fmb + (w * 16 + m15) * DD + q * 8;

    v4f acc0 = {0.f, 0.f, 0.f, 0.f};
    v4f acc1 = {0.f, 0.f, 0.f, 0.f};
    short8 afr[2][4];              // A-frag parity buffers (asm-pinned)
    float4 sw[2][2];               // wv parity buffers (asm-pinned)

    // prologue: issue wv(0)->sw[0], wv(1)->sw[1], afr(0)->afr[0]  (8 loads)
    gl4f(sw[0][0], wbase);
    gl4f(sw[0][1], wbase + 8192);
    {
        const float* p = wbase + (size_t)128 * 8192;
        gl4f(sw[1][0], p);
        gl4f(sw[1][1], p + 8192);
    }
#pragma unroll
    for (int ks = 0; ks < 4; ++ks) gl4s(afr[0][ks], abase + ks * 32);

    asm volatile("s_waitcnt vmcnt(6)" ::: "memory");   // wv(0) landed
    __builtin_amdgcn_sched_barrier(0);
    {
        const float* f0 = (const float*)&sw[0][0];
        const float* f1 = (const float*)&sw[0][1];
#pragma unroll
        for (int j = 0; j < 4; ++j)
            *(unsigned*)&Ws[0][nq * 4 + j][2 * kp] = pack_bf16(f0[j], f1[j]);
    }
    BARSYNC();   // wv(1), afr(0) stay in flight

#pragma unroll
    for (int c = 0; c < 16; ++c) {
        const int P = c & 1, Q = 1 - P;
        // issue wv(c+2) into the parity slot freed last step
        if (c + 2 < 16) {
            const float* p = wbase + (size_t)(c + 2) * 128 * 8192;
            gl4f(sw[P][0], p);
            gl4f(sw[P][1], p + 8192);
        }
        // issue afr(c+1)
        if (c + 1 < 16) {
            const unsigned short* ap = abase + (c + 1) * 128;
            gl4s(afr[Q][0], ap);
            gl4s(afr[Q][1], ap + 32);
            gl4s(afr[Q][2], ap + 64);
            gl4s(afr[Q][3], ap + 96);
        }
        // retire the previous step's batch: wv(c+1) + afr(c) are now in registers
        if (c <= 13)      asm volatile("s_waitcnt vmcnt(6)" ::: "memory");
        else if (c == 14) asm volatile("s_waitcnt vmcnt(4)" ::: "memory");
        else              asm volatile("s_waitcnt vmcnt(0)" ::: "memory");
        __builtin_amdgcn_sched_barrier(0);
        // MFMA chunk c from Ws[P] with afr[P]
#pragma unroll
        for (int ks = 0; ks < 4; ++ks) {
            short8 b0 = *(const short8*)&Ws[P][m15][ks * 32 + q * 8];
            short8 b1 = *(const short8*)&Ws[P][16 + m15][ks * 32 + q * 8];
            acc0 = __builtin_amdgcn_mfma_f32_16x16x32_bf16(afr[P][ks], b0, acc0, 0, 0, 0);
            acc1 = __builtin_amdgcn_mfma_f32_16x16x32_bf16(afr[P][ks], b1, acc1, 0, 0, 0);
        }
        // stage wv(c+1) -> Ws[Q]
        if (c + 1 < 16) {
            const float* f0 = (const float*)&sw[Q][0];
            const float* f1 = (const float*)&sw[Q][1];
#pragma unroll
            for (int j = 0; j < 4; ++j)
                *(unsigned*)&Ws[Q][nq * 4 + j][2 * kp] = pack_bf16(f0[j], f1[j]);
        }
        BARSYNC();
    }

    // epilogue: |acc| -> marg atomics + label-select scatter. D layout: row=q*4+r, col=m15.
    const int vbase = (nb & 63) * 8;
    const int iblk = nb >> 6;
    const int j = m15 & 3;
    const int v0 = vbase + (m15 >> 2);   // col = m15
    const float* a0p = (const float*)&acc0;
    const float* a1p = (const float*)&acc1;
#pragma unroll
    for (int r = 0; r < 4; ++r) {
        int m = w * 16 + q * 4 + r;
        float a0 = fabsf(a0p[r]);        // col = m15       -> v0
        float a1 = fabsf(a1p[r]);        // col = 16 + m15  -> v0 + 4
        float s = a0 + a1;
        s += __shfl_xor(s, 4);
        s += __shfl_xor(s, 8);
        if ((lane & 12) == 0) atomicAdd(&margA[m * 16 + iblk * 4 + j], s);
#pragma unroll
        for (int t = 0; t < TT; ++t) {
            int lv = slab[m * 8 + t];
            if (lv == v0)     sel[(m * 8 + t) * 16 + iblk * 4 + j] = a0;
            if (lv == v0 + 4) sel[(m * 8 + t) * 16 + iblk * 4 + j] = a1;
        }
    }
}

// ---------------- phase D: chain products, normalizer, loss ----------------
__global__ __launch_bounds__(128) void phaseD(const float* __restrict__ alphaP,
                                              const float* __restrict__ betaP,
                                              const float* __restrict__ marg,
                                              const float* __restrict__ sel,
                                              float* __restrict__ out) {
    int b = threadIdx.x;
    const float* sb = sel + b * TT * 16;
    float res[16], tmp[16], mm[16], zm[16];
#pragma unroll
    for (int e = 0; e < 16; ++e) res[e] = sb[e];
    for (int t = 1; t < TT; ++t) {
        const float* m = sb + t * 16;
#pragma unroll
        for (int i = 0; i < 4; ++i)
#pragma unroll
            for (int jj = 0; jj < 4; ++jj) {
                float s = 0.f;
#pragma unroll
                for (int k = 0; k < 4; ++k) s += res[i * 4 + k] * m[k * 4 + jj];
                tmp[i * 4 + jj] = s;
            }
#pragma unroll
        for (int e = 0; e < 16; ++e) res[e] = tmp[e];
    }
#pragma unroll
    for (int e = 0; e < 16; ++e) { mm[e] = marg[b * 16 + e]; zm[e] = mm[e]; }
    for (int st = 0; st < TT; ++st) {
#pragma unroll
        for (int i = 0; i < 4; ++i)
#pragma unroll
            for (int jj = 0; jj < 4; ++jj) {
                float s = 0.f;
#pragma unroll
                for (int k = 0; k < 4; ++k) s += zm[i * 4 + k] * mm[k * 4 + jj];
                tmp[i * 4 + jj] = s;
            }
#pragma unroll
        for (int e = 0; e < 16; ++e) zm[e] = tmp[e];
    }
    float u = 0.f, z = 0.f;
#pragma unroll
    for (int i = 0; i < 4; ++i) {
        float ai = fabsf(alphaP[b * 8 + i] + alphaP[b * 8 + 4 + i]);
#pragma unroll
        for (int jj = 0; jj < 4; ++jj) {
            float bj = fabsf(betaP[b * 8 + jj] + betaP[b * 8 + 4 + jj]);
            u += ai * res[i * 4 + jj] * bj;
            z += ai * zm[i * 4 + jj] * bj;
        }
    }
    float loss = logf(z) - logf(u);
    __shared__ float red[128];
    red[b] = loss;
    __syncthreads();
    for (int off = 64; off >= 1; off >>= 1) {
        if (b < off) red[b] += red[b + off];
        __syncthreads();
    }
    if (b == 0) out[0] = red[0] * (1.0f / BB);
}

extern "C" void kernel_launch(void* const* d_in, const int* in_sizes, int n_in,
                              void* d_out, int out_size, void* d_ws, size_t ws_size,
                              hipStream_t stream) {
    const float* inp     = (const float*)d_in[0];  // [128,8,2048]
    const int*   labels  = (const int*)d_in[1];    // [128,8]
    const float* w_alpha = (const float*)d_in[2];  // [2048,4]
    const float* w_beta  = (const float*)d_in[3];  // [2048,4]
    const float* wv      = (const float*)d_in[4];  // [2048,8192]
    float* out = (float*)d_out;

    float* ws     = (float*)d_ws;
    float* alphaP = ws;                        // 1024 floats
    float* betaP  = ws + 1024;                 // 1024 floats
    float* marg   = ws + 2048;                 // 2048 floats (zeroed by phaseA)
    float* sel    = ws + 4096;                 // 16384 floats (fully written by phaseB)
    unsigned short* fmb = (unsigned short*)(ws + 20480);  // 128*2048 bf16 = 131072 floats

    phaseA<<<256, 256, 0, stream>>>(inp, w_alpha, w_beta, fmb, alphaP, betaP, marg);
    phaseB<<<256, 512, 0, stream>>>(fmb, wv, labels, marg, sel);
    phaseD<<<1, 128, 0, stream>>>(alphaP, betaP, marg, sel, out);
}